// Round 7
// baseline (151.547 us; speedup 1.0000x reference)
//
#include <hip/hip_runtime.h>
#include <math.h>

// Problem constants (fixed by setup_inputs): B=4, H=W=D=128, C=2, fp32.
#define BN 4
#define HN 128
#define WN 128
#define DN 128

// v8: v7's proven structure (32j x 16k tile, coalesced LDS-transposed stores,
// asm-forced gather MLP, validated folded fp64 math -- absmax bit-identical
// 1.578125 for 5 rounds) with 4 voxels/thread and staged vmcnt waits.
//
// v7 post-mortem: FETCH 28.9MB/dispatch vs ~537MB gather traffic => ~5-8% of
// taps pay ~900cy HBM latency; vmcnt(0) waits on the MAX of 8 taps => ~40% of
// wave bodies stall ~900cy for only 2 voxels of work. v8 amortizes one
// max-latency over 4 voxels (16 taps in flight, same tile footprint so FETCH
// unchanged), issues loads inside Phase A (earlier, kills address liveness),
// and drains with vmcnt(12/8/4/0) so earlier combines hide the tail.

#define GLOAD16(dst, ptr) \
    asm volatile("global_load_dwordx4 %0, %1, off" : "=v"(dst) : "v"(ptr))
// Rule-#18 fence: volatile waitcnt (ordered vs the volatile loads) + full
// sched_barrier so no consumer is scheduled above its wait.
#define VMWAIT(n) do { \
    asm volatile("s_waitcnt vmcnt(" #n ")" ::: "memory"); \
    __builtin_amdgcn_sched_barrier(0); } while (0)

__global__ __launch_bounds__(128) void st_trilerp_kernel(
    const float* __restrict__ image,   // [B*H*W*D, 2] viewed flat
    const float* __restrict__ theta,   // [B, 3, 4]
    float* __restrict__ out)           // [B*H*W*D, 2]
{
    const int bi = blockIdx.z;         // b*H + i  (uniform per block)
    const int b  = bi >> 7;
    const int i  = bi & (HN - 1);
    const int j0 = blockIdx.y << 5;    // 32-wide j tile
    const int k0 = blockIdx.x << 4;    // 16-wide k tile

    const int tid = threadIdx.x;       // 0..127
    const int jj  = tid & 31;          // x-axis fastest across lanes (loads)
    const int kg  = tid >> 5;          // 0..3 groups of 4 consecutive k
    const int j   = j0 + jj;
    const int kb  = k0 + (kg << 2);

    // np.linspace(-1, 1, 128) float64: v = i*(2/127) - 1, endpoint EXACT.
    const double step = 2.0 / 127.0;
    const double X = (j == WN - 1) ? 1.0 : (double)j * step - 1.0;
    const double Y = (i == HN - 1) ? 1.0 : (double)i * step - 1.0;

    const float* th = theta + b * 12;  // b uniform -> scalar loads
    const double t0 = (double)th[0], t1 = (double)th[1], t2  = (double)th[2],  t3  = (double)th[3];
    const double t4 = (double)th[4], t5 = (double)th[5], t6  = (double)th[6],  t7  = (double)th[7];
    const double t8 = (double)th[8], t9 = (double)th[9], t10 = (double)th[10], t11 = (double)th[11];

    // Folded (validated): coord = P*k + Q, with
    // P = (64*step)*th2 = (128/127)*th2,  Q = 64*((th0*X+th1*Y) + th3 - th2) + 64
    const double KST = 128.0 / 127.0;
    const double Px = t2  * KST, Qx = fma(64.0, (t0*X + t1*Y) + t3  - t2,  64.0);
    const double Py = t6  * KST, Qy = fma(64.0, (t4*X + t5*Y) + t7  - t6,  64.0);
    const double Pz = t10 * KST, Qz = fma(64.0, (t8*X + t9*Y) + t11 - t10, 64.0);

    const int base = b * (HN * WN * DN);
    const float2* __restrict__ img2 = (const float2*)image;

    float4 q00[4], q10[4], q01[4], q11[4];
    float  wxL[4], wxH[4], wy0[4], wy1[4], wz0[4], wzA[4];

    // ---- Phase A: per voxel: coords, weights, addresses, ISSUE 4 gathers.
    // Volatile asm keeps all 16 loads in issue order with no waits between;
    // issuing inside the loop starts tap 0 ~100cy earlier and kills address
    // register liveness immediately.
#pragma unroll
    for (int c = 0; c < 4; ++c) {
        const double kd = (double)(kb + c);
        const double x = fma(Px, kd, Qx);
        const double y = fma(Py, kd, Qy);
        const double z = fma(Pz, kd, Qz);

        // floor, +1, then clip (x1 derives from UNclipped x0+1) -- fp64 path
        const double xf = floor(x), yf = floor(y), zf = floor(z);
        const int x0u = (int)xf, y0u = (int)yf, z0u = (int)zf;
        const int x0 = min(max(x0u,     0), WN - 1);
        const int x1 = min(max(x0u + 1, 0), WN - 1);
        const int y0 = min(max(y0u,     0), HN - 1);
        const int y1 = min(max(y0u + 1, 0), HN - 1);
        const int z0 = min(max(z0u,     0), DN - 1);
        const int z1 = min(max(z0u + 1, 0), DN - 1);

        // f32 weight factors (validated; reference's wzA = z1 - z0)
        const float xs = (float)x, ys = (float)y, zs = (float)z;
        const float wx0f = (float)x1 - xs, wx1f = xs - (float)x0;
        wy0[c] = (float)y1 - ys;  wy1[c] = ys - (float)y0;
        wz0[c] = (float)z1 - zs;  wzA[c] = (float)(z1 - z0);

        // x-pair select weights: normal (T,F)->(wx0,wx1); both-low (T,T)->
        // (wx0+wx1,0); both-high (F,F)->(0,wx0+wx1). Matches reference exactly.
        const int xb  = min(x0, WN - 2);            // 0..126, pair in-bounds
        const bool lo0 = (x0 == xb), lo1 = (x1 == xb);
        wxL[c] = (lo0 ? wx0f : 0.0f) + (lo1 ? wx1f : 0.0f);
        wxH[c] = (lo0 ? 0.0f : wx0f) + (lo1 ? 0.0f : wx1f);

        // flat idx = base + y*W + z*(W*H) + x   (W=128, W*H=16384)
        const int rb = base + (y0 << 7) + (z0 << 14) + xb;
        const int dy = (y1 - y0) << 7;
        const int dz = (z1 - z0) << 14;
        GLOAD16(q00[c], img2 + rb);
        GLOAD16(q10[c], img2 + rb + dy);
        GLOAD16(q01[c], img2 + rb + dz);
        GLOAD16(q11[c], img2 + rb + dy + dz);
    }

    // LDS transpose tile (v7's proven store path, widened to 4 k-rows/thread).
    __shared__ float2 tile[16][33];    // pitch 33 float2 breaks pow-2 stride
    const int kk = kg << 2;

    // ---- Phase B: staged drain -- combine voxel c once its 4 taps landed,
    // while the remaining taps are still in flight.
#define COMBINE(c) do { \
        const float g00x = wxL[c]*q00[c].x + wxH[c]*q00[c].z; \
        const float g00y = wxL[c]*q00[c].y + wxH[c]*q00[c].w; \
        const float g10x = wxL[c]*q10[c].x + wxH[c]*q10[c].z; \
        const float g10y = wxL[c]*q10[c].y + wxH[c]*q10[c].w; \
        const float g01x = wxL[c]*q01[c].x + wxH[c]*q01[c].z; \
        const float g01y = wxL[c]*q01[c].y + wxH[c]*q01[c].w; \
        const float g11x = wxL[c]*q11[c].x + wxH[c]*q11[c].z; \
        const float g11y = wxL[c]*q11[c].y + wxH[c]*q11[c].w; \
        const float h0x = wy0[c]*g00x + wy1[c]*g10x; \
        const float h0y = wy0[c]*g00y + wy1[c]*g10y; \
        const float h1x = wy0[c]*g01x + wy1[c]*g11x; \
        const float h1y = wy0[c]*g01y + wy1[c]*g11y; \
        tile[kk + c][jj] = make_float2(wz0[c]*h0x + wzA[c]*h1x, \
                                       wz0[c]*h0y + wzA[c]*h1y); \
    } while (0)

    VMWAIT(12); COMBINE(0);
    VMWAIT(8);  COMBINE(1);
    VMWAIT(4);  COMBINE(2);
    VMWAIT(0);  COMBINE(3);
#undef COMBINE

    __syncthreads();

    // ---- Phase C: coalesced stores. row = j (32 rows), 8 float4 per row;
    // each thread stores 2 float4 (cols c0 and c0+4). A wave's store instr
    // covers 16 rows x 64B; the pair completes full 128B lines (L2 combines;
    // WRITE_SIZE was exactly 64MB with this class of pattern in v7).
    const int row = tid >> 2;          // 0..31  (j index within tile)
    const int c0  = tid & 3;           // 0..3
#pragma unroll
    for (int s = 0; s < 2; ++s) {
        const int col = c0 + (s << 2);                 // float4 column 0..7
        const float2 a = tile[2*col + 0][row];
        const float2 d = tile[2*col + 1][row];
        const int oidx = (bi * WN + (j0 + row)) * DN + k0 + 2*col; // float2 units
        *(float4*)((float2*)out + oidx) = make_float4(a.x, a.y, d.x, d.y);
    }
}

extern "C" void kernel_launch(void* const* d_in, const int* in_sizes, int n_in,
                              void* d_out, int out_size, void* d_ws, size_t ws_size,
                              hipStream_t stream) {
    const float* image = (const float*)d_in[0];
    const float* theta = (const float*)d_in[1];
    float* out = (float*)d_out;

    dim3 grid(DN / 16, WN / 32, BN * HN);   // (8, 4, 512)
    st_trilerp_kernel<<<grid, 128, 0, stream>>>(image, theta, out);
}

// Round 9
// 138.275 us; speedup vs baseline: 1.0960x; 1.0960x over previous
//
#include <hip/hip_runtime.h>
#include <math.h>

// Problem constants (fixed by setup_inputs): B=4, H=W=D=128, C=2, fp32.
#define BN 4
#define HN 128
#define WN 128
#define DN 128

// v10 = v9 with the compile fix: __builtin_nontemporal_store requires a
// native clang vector type, not HIP's float4 class -> use
// ext_vector_type(4) float for the nt store. Same instruction
// (global_store_dwordx4 nt), same alignment. All else identical to v9:
//  1) NON-TEMPORAL output stores: output is write-once/read-never; nt keeps
//     it from evicting the 64MB image out of the 256MB L3. Target: FETCH
//     28.9MB -> ~0, gather miss tail ~900cy -> L3-hit.
//  2) XCD-AWARE BIJECTIVE SWIZZLE (16384 blocks = 8 XCDs x 2048 exact):
//     each XCD owns a contiguous 64-bi chunk, bi-sequential; resident blocks
//     per XCD span ~8 bi ~= 2MB gather footprint -> fits 4MB L2; consecutive
//     bi share a y-plane -> fetched once per XCD instead of ~8x.
//  3) SPLIT DRAIN vmcnt(4)/vmcnt(0): voxel-0 combine (~80cy) hides under
//     voxel-1's latency tail. (v8 proved 4vox/16-deep is past the VGPR knee;
//     per-thread structure stays at v7's 2vox/8-deep.)
// Math bit-identical for 6 rounds (absmax 1.578125).

typedef float f32x4 __attribute__((ext_vector_type(4)));

#define GLOAD16(dst, ptr) \
    asm volatile("global_load_dwordx4 %0, %1, off" : "=v"(dst) : "v"(ptr))
// Rule-#18 fence: volatile waitcnt (ordered vs the volatile loads) then
// sched_barrier(0) so no consumer is scheduled above the wait.
#define VMWAIT(n) do { \
    asm volatile("s_waitcnt vmcnt(" #n ")" ::: "memory"); \
    __builtin_amdgcn_sched_barrier(0); } while (0)

__global__ __launch_bounds__(256) void st_trilerp_kernel(
    const float* __restrict__ image,   // [B*H*W*D, 2] viewed flat
    const float* __restrict__ theta,   // [B, 3, 4]
    float* __restrict__ out)           // [B*H*W*D, 2]
{
    // ---- XCD-aware bijective remap (1D grid, 16384 blocks, 8 XCDs) ----
    // HW round-robins consecutive blockIdx across XCDs; after remap, XCD x
    // processes wgid = x*2048 .. x*2048+2047 in order => bi-sequential chunks.
    const int orig = blockIdx.x;
    const int wgid = ((orig & 7) << 11) | (orig >> 3);
    const int bi  = wgid >> 5;         // 0..511  = b*H + i (uniform per block)
    const int rem = wgid & 31;
    const int b  = bi >> 7;
    const int i  = bi & (HN - 1);
    const int j0 = (rem >> 3) << 5;    // 32-wide j tile (4 tiles)
    const int k0 = (rem & 7) << 4;     // 16-wide k tile (8 tiles)

    const int tid = threadIdx.x;       // 0..255
    const int jj  = tid & 31;          // x-axis fastest across lanes (loads)
    const int kg  = tid >> 5;          // 0..7 groups of 2 consecutive k
    const int j   = j0 + jj;
    const int kb  = k0 + (kg << 1);

    // np.linspace(-1, 1, 128) float64: v = i*(2/127) - 1, endpoint EXACT.
    const double step = 2.0 / 127.0;
    const double X = (j == WN - 1) ? 1.0 : (double)j * step - 1.0;
    const double Y = (i == HN - 1) ? 1.0 : (double)i * step - 1.0;

    const float* th = theta + b * 12;  // b uniform -> scalar loads
    const double t0 = (double)th[0], t1 = (double)th[1], t2  = (double)th[2],  t3  = (double)th[3];
    const double t4 = (double)th[4], t5 = (double)th[5], t6  = (double)th[6],  t7  = (double)th[7];
    const double t8 = (double)th[8], t9 = (double)th[9], t10 = (double)th[10], t11 = (double)th[11];

    // Folded (validated): coord = P*k + Q, with
    // P = (64*step)*th2 = (128/127)*th2,  Q = 64*((th0*X+th1*Y) + th3 - th2) + 64
    const double KST = 128.0 / 127.0;
    const double Px = t2  * KST, Qx = fma(64.0, (t0*X + t1*Y) + t3  - t2,  64.0);
    const double Py = t6  * KST, Qy = fma(64.0, (t4*X + t5*Y) + t7  - t6,  64.0);
    const double Pz = t10 * KST, Qz = fma(64.0, (t8*X + t9*Y) + t11 - t10, 64.0);

    const int base = b * (HN * WN * DN);
    const float2* __restrict__ img2 = (const float2*)image;

    int   r00[2], r10[2], r01[2], r11[2];
    float wxL[2], wxH[2], wy0[2], wy1[2], wz0[2], wzA[2];

    // ---- Phase A: coords, weights, ADDRESSES ONLY (no memory ops) ----
#pragma unroll
    for (int c = 0; c < 2; ++c) {
        const double kd = (double)(kb + c);
        const double x = fma(Px, kd, Qx);
        const double y = fma(Py, kd, Qy);
        const double z = fma(Pz, kd, Qz);

        // floor, +1, then clip (x1 derives from UNclipped x0+1) -- fp64 path
        const double xf = floor(x), yf = floor(y), zf = floor(z);
        const int x0u = (int)xf, y0u = (int)yf, z0u = (int)zf;
        const int x0 = min(max(x0u,     0), WN - 1);
        const int x1 = min(max(x0u + 1, 0), WN - 1);
        const int y0 = min(max(y0u,     0), HN - 1);
        const int y1 = min(max(y0u + 1, 0), HN - 1);
        const int z0 = min(max(z0u,     0), DN - 1);
        const int z1 = min(max(z0u + 1, 0), DN - 1);

        // f32 weight factors (validated; reference's wzA = z1 - z0)
        const float xs = (float)x, ys = (float)y, zs = (float)z;
        const float wx0f = (float)x1 - xs, wx1f = xs - (float)x0;
        wy0[c] = (float)y1 - ys;  wy1[c] = ys - (float)y0;
        wz0[c] = (float)z1 - zs;  wzA[c] = (float)(z1 - z0);

        // x-pair select weights: normal (T,F)->(wx0,wx1); both-low (T,T)->
        // (wx0+wx1,0); both-high (F,F)->(0,wx0+wx1). Matches reference exactly.
        const int xb  = min(x0, WN - 2);            // 0..126, pair in-bounds
        const bool lo0 = (x0 == xb), lo1 = (x1 == xb);
        wxL[c] = (lo0 ? wx0f : 0.0f) + (lo1 ? wx1f : 0.0f);
        wxH[c] = (lo0 ? 0.0f : wx0f) + (lo1 ? 0.0f : wx1f);

        // flat idx = base + y*W + z*(W*H) + x   (W=128, W*H=16384)
        const int rb = base + (y0 << 7) + (z0 << 14) + xb;
        const int dy = (y1 - y0) << 7;
        const int dz = (z1 - z0) << 14;
        r00[c] = rb;
        r10[c] = rb + dy;
        r01[c] = rb + dz;
        r11[c] = rb + dy + dz;
    }

    // ---- Phase B: 8 gathers forced in flight; voxel-0 taps first ----
    float4 q00[2], q10[2], q01[2], q11[2];
    GLOAD16(q00[0], img2 + r00[0]);
    GLOAD16(q10[0], img2 + r10[0]);
    GLOAD16(q01[0], img2 + r01[0]);
    GLOAD16(q11[0], img2 + r11[0]);
    GLOAD16(q00[1], img2 + r00[1]);
    GLOAD16(q10[1], img2 + r10[1]);
    GLOAD16(q01[1], img2 + r01[1]);
    GLOAD16(q11[1], img2 + r11[1]);

    __shared__ float2 tile[16][33];    // pitch 33 float2 breaks pow-2 stride
    const int kk = kg << 1;

    // ---- Phase C: split drain; combine voxel 0 under voxel 1's tail ----
#define COMBINE(c) do { \
        const float g00x = wxL[c]*q00[c].x + wxH[c]*q00[c].z; \
        const float g00y = wxL[c]*q00[c].y + wxH[c]*q00[c].w; \
        const float g10x = wxL[c]*q10[c].x + wxH[c]*q10[c].z; \
        const float g10y = wxL[c]*q10[c].y + wxH[c]*q10[c].w; \
        const float g01x = wxL[c]*q01[c].x + wxH[c]*q01[c].z; \
        const float g01y = wxL[c]*q01[c].y + wxH[c]*q01[c].w; \
        const float g11x = wxL[c]*q11[c].x + wxH[c]*q11[c].z; \
        const float g11y = wxL[c]*q11[c].y + wxH[c]*q11[c].w; \
        const float h0x = wy0[c]*g00x + wy1[c]*g10x; \
        const float h0y = wy0[c]*g00y + wy1[c]*g10y; \
        const float h1x = wy0[c]*g01x + wy1[c]*g11x; \
        const float h1y = wy0[c]*g01y + wy1[c]*g11y; \
        tile[kk + c][jj] = make_float2(wz0[c]*h0x + wzA[c]*h1x, \
                                       wz0[c]*h0y + wzA[c]*h1y); \
    } while (0)

    VMWAIT(4); COMBINE(0);
    VMWAIT(0); COMBINE(1);
#undef COMBINE

    __syncthreads();

    // ---- Phase D: coalesced NON-TEMPORAL stores (v7's exact pattern).
    // Output is write-once/read-never: nt keeps it out of L3 so the image
    // stays resident (FETCH -> ~0 target). WRITE_SIZE unchanged (compulsory).
    const int row = tid >> 3;          // 0..31  (j index within tile)
    const int q   = tid & 7;           // 0..7   (float4 column: 2 k each)
    const float2 a  = tile[2*q + 0][row];
    const float2 bb = tile[2*q + 1][row];
    const int oidx = (bi * WN + (j0 + row)) * DN + k0 + 2*q;   // float2 units
    f32x4 val; val.x = a.x; val.y = a.y; val.z = bb.x; val.w = bb.y;
    __builtin_nontemporal_store(val, (f32x4*)((float2*)out + oidx));
}

extern "C" void kernel_launch(void* const* d_in, const int* in_sizes, int n_in,
                              void* d_out, int out_size, void* d_ws, size_t ws_size,
                              hipStream_t stream) {
    const float* image = (const float*)d_in[0];
    const float* theta = (const float*)d_in[1];
    float* out = (float*)d_out;

    st_trilerp_kernel<<<dim3(16384), 256, 0, stream>>>(image, theta, out);
}